// Round 1
// 273.251 us; speedup vs baseline: 1.1420x; 1.1420x over previous
//
#include <hip/hip_runtime.h>
#include <hip/hip_bf16.h>

#define NNODES 50000
#define NEDGES 1600000
#define NBIN   782      // ceil(50000/64) destination bins, 64 nodes each
#define CAPB   2880     // bin slot capacity; mean 2046, sigma ~45 (mean + 18 sigma)
#define BCHUNK 2000
#define NBBLK  800      // NBBLK * BCHUNK == NEDGES
#define BCPAD  16       // bincur padded to one int per 64B line (atomic contention)

__device__ __forceinline__ float bf2f(unsigned short u) {
    union { unsigned int i; float f; } x; x.i = ((unsigned int)u) << 16; return x.f;
}

// ---------------------------------------------------------------------------
// 1) Single-read LDS-staged binning. Each block owns 2000 edges: stage packed
//    (row | (c&63)<<16 | bin<<22) in LDS with int4 loads while building the
//    per-block histogram; reserve per-bin runs with one padded global atomic
//    per nonzero bin; place from LDS. Edges are read from HBM exactly once
//    (vs 16 scans in the old 8-group two-pass design).
__global__ __launch_bounds__(256) void k_bin(const int* __restrict__ edges,
                                             int* __restrict__ bincur,
                                             int* __restrict__ binned) {
    __shared__ int pk[BCHUNK];
    __shared__ int hist[NBIN];
    __shared__ int gbase[NBIN];
    __shared__ int lcnt[NBIN];
    int t = threadIdx.x;
    int e0 = blockIdx.x * BCHUNK;
    for (int i = t; i < NBIN; i += 256) { hist[i] = 0; lcnt[i] = 0; }
    __syncthreads();
    // stage + histogram in one pass (16B vector loads; BCHUNK % 4 == 0)
    for (int i = t * 4; i < BCHUNK; i += 1024) {
        int4 r4 = *(const int4*)&edges[e0 + i];
        int4 c4 = *(const int4*)&edges[NEDGES + e0 + i];
        int b0 = c4.x >> 6, b1 = c4.y >> 6, b2 = c4.z >> 6, b3 = c4.w >> 6;
        pk[i + 0] = r4.x | ((c4.x & 63) << 16) | (b0 << 22);
        pk[i + 1] = r4.y | ((c4.y & 63) << 16) | (b1 << 22);
        pk[i + 2] = r4.z | ((c4.z & 63) << 16) | (b2 << 22);
        pk[i + 3] = r4.w | ((c4.w & 63) << 16) | (b3 << 22);
        atomicAdd(&hist[b0], 1);
        atomicAdd(&hist[b1], 1);
        atomicAdd(&hist[b2], 1);
        atomicAdd(&hist[b3], 1);
    }
    __syncthreads();
    for (int i = t; i < NBIN; i += 256) {
        int h = hist[i];
        gbase[i] = (h > 0) ? atomicAdd(&bincur[i * BCPAD], h) : 0;
    }
    __syncthreads();
    for (int i = t; i < BCHUNK; i += 256) {
        int v = pk[i];
        int bin = ((unsigned)v) >> 22;
        int p = gbase[bin] + atomicAdd(&lcnt[bin], 1);
        if (p < CAPB) binned[bin * CAPB + p] = v & 0x3FFFFF;
    }
}

// ---------------------------------------------------------------------------
// 2) Per-bin LDS counting sort -> node-contiguous CSR (coalesced writes).
//    Fused: dinv, rowptr/cnt, pre-scaled bf16 x0s rows.
__global__ __launch_bounds__(256) void k_sortbin(const int* __restrict__ bincur,
                                                 const int* __restrict__ binned,
                                                 const float* __restrict__ x,
                                                 int* __restrict__ rowptr,
                                                 int* __restrict__ cntn,
                                                 float* __restrict__ dinv,
                                                 unsigned short* __restrict__ x0s,
                                                 int* __restrict__ csr) {
    __shared__ int h[64];
    __shared__ int off[64];
    __shared__ int cur[64];
    __shared__ float dv[64];
    __shared__ int stage[CAPB];
    int t = threadIdx.x, bin = blockIdx.x;
    int wave = t >> 6, lane = t & 63;
    if (t < 64) h[t] = 0;
    __syncthreads();
    int len = min(bincur[bin * BCPAD], CAPB);
    const int* __restrict__ bb = binned + bin * CAPB;
    for (int e = t; e < len; e += 256)
        atomicAdd(&h[bb[e] >> 16], 1);
    __syncthreads();
    if (t == 0) {
        int s = 0;
        for (int i = 0; i < 64; ++i) { off[i] = s; cur[i] = s; s += h[i]; }
    }
    __syncthreads();
    if (t < 64) {
        int n = bin * 64 + t;
        float dc = rsqrtf((float)(h[t] + 1));
        dv[t] = dc;
        if (n < NNODES) {
            dinv[n] = dc;
            rowptr[n] = bin * CAPB + off[t];
            cntn[n] = h[t];
        }
    }
    __syncthreads();
    for (int e = t; e < len; e += 256) {
        int v = bb[e];
        int p = atomicAdd(&cur[v >> 16], 1);
        stage[p] = v & 0xFFFF;
    }
    __syncthreads();
    for (int e = t; e < len; e += 256)
        csr[bin * CAPB + e] = stage[e];
    // pre-scaled bf16 rows: x0s[n][f] = bf16(x[n][f] * dinv[n])
    for (int i = wave; i < 64; i += 4) {
        int n = bin * 64 + i;
        if (n < NNODES) {
            __hip_bfloat16 v = __float2bfloat16(x[n * 256 + lane] * dv[i]);
            x0s[n * 64 + lane] = *(unsigned short*)&v;
        }
    }
}

// ---------------------------------------------------------------------------
// 3) Per-node gather: one wave per node, lane = feature, register accumulate.
//    50K waves, zero LDS, VGPR ~32 -> full occupancy, max loads in flight.
__global__ __launch_bounds__(256) void k_gather(const unsigned short* __restrict__ x0s,
                                                const int* __restrict__ rowptr,
                                                const int* __restrict__ cntn,
                                                const float* __restrict__ dinv,
                                                const int* __restrict__ csr,
                                                float* __restrict__ agg) {
    int wave = threadIdx.x >> 6, lane = threadIdx.x & 63;
    int n = blockIdx.x * 4 + wave;          // 12500 * 4 = 50000 exactly
    int start = rowptr[n], len = cntn[n];
    float acc0 = bf2f(x0s[n * 64 + lane]);  // self-loop (pre-scaled)
    float acc1 = 0.0f;
    for (int base = 0; base < len; base += 64) {
        int m = min(len - base, 64);
        int idx = (lane < m) ? csr[start + base + lane] : 0;  // one coalesced load
        int j = 0;
        for (; j + 8 <= m; j += 8) {
            int r0 = __shfl(idx, j + 0), r1 = __shfl(idx, j + 1);
            int r2 = __shfl(idx, j + 2), r3 = __shfl(idx, j + 3);
            int r4 = __shfl(idx, j + 4), r5 = __shfl(idx, j + 5);
            int r6 = __shfl(idx, j + 6), r7 = __shfl(idx, j + 7);
            float f0 = bf2f(x0s[r0 * 64 + lane]);
            float f1 = bf2f(x0s[r1 * 64 + lane]);
            float f2 = bf2f(x0s[r2 * 64 + lane]);
            float f3 = bf2f(x0s[r3 * 64 + lane]);
            float f4 = bf2f(x0s[r4 * 64 + lane]);
            float f5 = bf2f(x0s[r5 * 64 + lane]);
            float f6 = bf2f(x0s[r6 * 64 + lane]);
            float f7 = bf2f(x0s[r7 * 64 + lane]);
            acc0 += (f0 + f1) + (f2 + f3);
            acc1 += (f4 + f5) + (f6 + f7);
        }
        for (; j < m; ++j) {
            int r = __shfl(idx, j);
            acc0 += bf2f(x0s[r * 64 + lane]);
        }
    }
    agg[n * 64 + lane] = (acc0 + acc1) * dinv[n];
}

// ---------------------------------------------------------------------------
// 4) per-head 64x64 linear + bias + relu, dual store.
__global__ __launch_bounds__(256) void k_gemm(const float* __restrict__ agg,
                                              const float* __restrict__ W,
                                              const float* __restrict__ b,
                                              float* __restrict__ out0,
                                              float* __restrict__ out1) {
    int t = threadIdx.x;
    int h = t >> 6, o = t & 63;
    float wreg[64];
    #pragma unroll
    for (int f = 0; f < 64; ++f) wreg[f] = W[h * 4096 + f * 64 + o];
    float bias = b[t];
    int n0 = blockIdx.x * 8;   // 6250 * 8 = 50000 exactly
    for (int i = 0; i < 8; ++i) {
        int n = n0 + i;
        const float* __restrict__ arow = agg + n * 64;   // block-uniform address
        float acc = bias;
        #pragma unroll
        for (int f = 0; f < 64; ++f) acc = fmaf(arow[f], wreg[f], acc);
        float v = fmaxf(acc, 0.0f);
        __builtin_nontemporal_store(v, &out0[n * 256 + t]);
        __builtin_nontemporal_store(v, &out1[n * 256 + t]);
    }
}

// ---------------------------------------------------------------------------

extern "C" void kernel_launch(void* const* d_in, const int* in_sizes, int n_in,
                              void* d_out, int out_size, void* d_ws, size_t ws_size,
                              hipStream_t stream) {
    const float* x     = (const float*)d_in[0];   // (50000, 256) f32
    const int*   edges = (const int*)d_in[1];     // (2, 1600000) int32
    const float* W     = (const float*)d_in[2];   // (4, 64, 64) f32
    const float* b     = (const float*)d_in[3];   // (4, 64) f32

    float* out0 = (float*)d_out;                   // x_cat (50000,256)
    float* out1 = out0 + (size_t)NNODES * 256;     // heads (50000,4,64) — same values

    // workspace layout (512B-aligned)
    char* ws = (char*)d_ws;
    int*            bincur = (int*)(ws + 0);            //    50,048 B (NBIN * 16 ints, padded)
    float*          dinv   = (float*)(ws + 50176);      //   200,000 B
    int*            rowptr = (int*)(ws + 250368);       //   200,000 B
    int*            cntn   = (int*)(ws + 450560);       //   200,000 B
    int*            binned = (int*)(ws + 650752);       // 9,008,640 B
    int*            csr    = (int*)(ws + 9659392);      // 9,008,640 B
    unsigned short* x0s    = (unsigned short*)(ws + 18668032);  // 6,400,000 B
    float*          agg    = (float*)(ws + 25068032);   // 12,800,000 B  (total ~37.9 MB)

    hipMemsetAsync(bincur, 0, NBIN * BCPAD * sizeof(int), stream);
    k_bin    <<<NBBLK, 256, 0, stream>>>(edges, bincur, binned);
    k_sortbin<<<NBIN, 256, 0, stream>>>(bincur, binned, x, rowptr, cntn, dinv, x0s, csr);
    k_gather <<<NNODES / 4, 256, 0, stream>>>(x0s, rowptr, cntn, dinv, csr, agg);
    k_gemm   <<<NNODES / 8, 256, 0, stream>>>(agg, W, b, out0, out1);
}

// Round 2
// 245.618 us; speedup vs baseline: 1.2705x; 1.1125x over previous
//
#include <hip/hip_runtime.h>
#include <hip/hip_bf16.h>

#define NNODES 50000
#define NEDGES 1600000
#define NBIN   782      // ceil(50000/64) destination bins, 64 nodes each
#define CAPB   2880     // per-bin total capacity; mean 2046, sigma ~45
#define SCAP   512      // per-(xcd,bin) sub-buffer capacity; mean ~256, sigma ~16
#define OVFCAP 65536    // overflow list entries (expected use: 0)
#define BCHUNK 2000
#define NBBLK  800      // NBBLK * BCHUNK == NEDGES

__device__ __forceinline__ float bf2f(unsigned short u) {
    union { unsigned int i; float f; } x; x.i = ((unsigned int)u) << 16; return x.f;
}

// ---------------------------------------------------------------------------
// 1) Single-read LDS-staged binning with per-XCD sub-buffers.
//    Each block stages 2000 packed edges (row | (c&63)<<16 | bin<<22) in LDS
//    while building a per-block histogram, reserves per-(xcd,bin) runs with
//    one global atomic per nonzero bin, and places from LDS.
//    binned[xcd][bin][*] and bincur[xcd][bin] are only ever written by blocks
//    on that XCD -> no cross-XCD L2 line ping-pong on the scattered stores,
//    8x less serialization per atomic counter. Rare sub-buffer overflow goes
//    to a global list drained by k_sortbin.
__global__ __launch_bounds__(256) void k_bin(const int* __restrict__ edges,
                                             int* __restrict__ bincur,
                                             int* __restrict__ ovfcnt,
                                             int* __restrict__ ovf,
                                             int* __restrict__ binned) {
    __shared__ int pk[BCHUNK];
    __shared__ int hist[NBIN];
    __shared__ int gbase[NBIN];
    __shared__ int lcnt[NBIN];
    int t = threadIdx.x;
    int e0 = blockIdx.x * BCHUNK;
    unsigned xcd;
    asm volatile("s_getreg_b32 %0, hwreg(HW_REG_XCC_ID)" : "=s"(xcd));
    xcd &= 7;
    for (int i = t; i < NBIN; i += 256) { hist[i] = 0; lcnt[i] = 0; }
    __syncthreads();
    // stage + histogram in one pass (16B vector loads; BCHUNK % 4 == 0)
    for (int i = t * 4; i < BCHUNK; i += 1024) {
        int4 r4 = *(const int4*)&edges[e0 + i];
        int4 c4 = *(const int4*)&edges[NEDGES + e0 + i];
        int b0 = c4.x >> 6, b1 = c4.y >> 6, b2 = c4.z >> 6, b3 = c4.w >> 6;
        pk[i + 0] = r4.x | ((c4.x & 63) << 16) | (b0 << 22);
        pk[i + 1] = r4.y | ((c4.y & 63) << 16) | (b1 << 22);
        pk[i + 2] = r4.z | ((c4.z & 63) << 16) | (b2 << 22);
        pk[i + 3] = r4.w | ((c4.w & 63) << 16) | (b3 << 22);
        atomicAdd(&hist[b0], 1);
        atomicAdd(&hist[b1], 1);
        atomicAdd(&hist[b2], 1);
        atomicAdd(&hist[b3], 1);
    }
    __syncthreads();
    for (int i = t; i < NBIN; i += 256) {
        int h = hist[i];
        gbase[i] = (h > 0) ? atomicAdd(&bincur[xcd * NBIN + i], h) : 0;
    }
    __syncthreads();
    for (int i = t; i < BCHUNK; i += 256) {
        int v = pk[i];
        int bin = ((unsigned)v) >> 22;
        int p = gbase[bin] + atomicAdd(&lcnt[bin], 1);
        if (p < SCAP) {
            binned[(xcd * NBIN + bin) * SCAP + p] = v & 0x3FFFFF;
        } else {
            int op = atomicAdd(ovfcnt, 1);
            if (op < OVFCAP) ovf[op] = v;   // keep bin bits for sortbin filter
        }
    }
}

// ---------------------------------------------------------------------------
// 2) Per-bin LDS counting sort over the 8 XCD sub-buffers (+ overflow list)
//    -> node-contiguous CSR (coalesced writes). Fused: dinv, rowptr/cnt,
//    pre-scaled bf16 x0s rows. Wave-parallel shuffle scan for the prefix.
__global__ __launch_bounds__(256) void k_sortbin(const int* __restrict__ bincur,
                                                 const int* __restrict__ binned,
                                                 const int* __restrict__ ovfcnt,
                                                 const int* __restrict__ ovf,
                                                 const float* __restrict__ x,
                                                 int* __restrict__ rowptr,
                                                 int* __restrict__ cntn,
                                                 float* __restrict__ dinv,
                                                 unsigned short* __restrict__ x0s,
                                                 int* __restrict__ csr) {
    __shared__ int h[64];
    __shared__ int off[64];
    __shared__ int cur[64];
    __shared__ float dv[64];
    __shared__ int slen[8];
    __shared__ int stage[CAPB];
    int t = threadIdx.x, bin = blockIdx.x;
    int wave = t >> 6, lane = t & 63;
    if (t < 64) h[t] = 0;
    if (t < 8) slen[t] = min(bincur[t * NBIN + bin], SCAP);
    __syncthreads();
    int novf = ovfcnt[0];
    for (int s = 0; s < 8; ++s) {
        const int* __restrict__ bb = binned + (s * NBIN + bin) * SCAP;
        int len = slen[s];
        for (int e = t; e < len; e += 256)
            atomicAdd(&h[bb[e] >> 16], 1);
    }
    for (int e = t; e < novf; e += 256) {
        int v = ovf[e];
        if (((unsigned)v >> 22) == (unsigned)bin) atomicAdd(&h[(v >> 16) & 63], 1);
    }
    __syncthreads();
    if (t < 64) {
        int v = h[t];
        int inc = v;
        #pragma unroll
        for (int d = 1; d < 64; d <<= 1) {
            int u = __shfl_up(inc, d);
            if (lane >= d) inc += u;
        }
        int ex = inc - v;
        off[t] = ex;
        cur[t] = ex;
        float dc = rsqrtf((float)(v + 1));
        dv[t] = dc;
        int n = bin * 64 + t;
        if (n < NNODES) {
            dinv[n] = dc;
            rowptr[n] = bin * CAPB + ex;
            cntn[n] = v;
        }
    }
    __syncthreads();
    for (int s = 0; s < 8; ++s) {
        const int* __restrict__ bb = binned + (s * NBIN + bin) * SCAP;
        int len = slen[s];
        for (int e = t; e < len; e += 256) {
            int v = bb[e];
            int p = atomicAdd(&cur[v >> 16], 1);
            if (p < CAPB) stage[p] = v & 0xFFFF;
        }
    }
    for (int e = t; e < novf; e += 256) {
        int v = ovf[e];
        if (((unsigned)v >> 22) == (unsigned)bin) {
            int p = atomicAdd(&cur[(v >> 16) & 63], 1);
            if (p < CAPB) stage[p] = v & 0xFFFF;
        }
    }
    __syncthreads();
    int total = min(off[63] + h[63], CAPB);
    for (int e = t; e < total; e += 256)
        csr[bin * CAPB + e] = stage[e];
    // pre-scaled bf16 rows: x0s[n][f] = bf16(x[n][f] * dinv[n])
    for (int i = wave; i < 64; i += 4) {
        int n = bin * 64 + i;
        if (n < NNODES) {
            __hip_bfloat16 v = __float2bfloat16(x[n * 256 + lane] * dv[i]);
            x0s[n * 64 + lane] = *(unsigned short*)&v;
        }
    }
}

// ---------------------------------------------------------------------------
// 3) Per-node gather: one wave per node, lane = feature, register accumulate.
//    50K waves, zero LDS, VGPR ~32 -> full occupancy, max loads in flight.
__global__ __launch_bounds__(256) void k_gather(const unsigned short* __restrict__ x0s,
                                                const int* __restrict__ rowptr,
                                                const int* __restrict__ cntn,
                                                const float* __restrict__ dinv,
                                                const int* __restrict__ csr,
                                                float* __restrict__ agg) {
    int wave = threadIdx.x >> 6, lane = threadIdx.x & 63;
    int n = blockIdx.x * 4 + wave;          // 12500 * 4 = 50000 exactly
    int start = rowptr[n], len = cntn[n];
    float acc0 = bf2f(x0s[n * 64 + lane]);  // self-loop (pre-scaled)
    float acc1 = 0.0f;
    for (int base = 0; base < len; base += 64) {
        int m = min(len - base, 64);
        int idx = (lane < m) ? csr[start + base + lane] : 0;  // one coalesced load
        int j = 0;
        for (; j + 8 <= m; j += 8) {
            int r0 = __shfl(idx, j + 0), r1 = __shfl(idx, j + 1);
            int r2 = __shfl(idx, j + 2), r3 = __shfl(idx, j + 3);
            int r4 = __shfl(idx, j + 4), r5 = __shfl(idx, j + 5);
            int r6 = __shfl(idx, j + 6), r7 = __shfl(idx, j + 7);
            float f0 = bf2f(x0s[r0 * 64 + lane]);
            float f1 = bf2f(x0s[r1 * 64 + lane]);
            float f2 = bf2f(x0s[r2 * 64 + lane]);
            float f3 = bf2f(x0s[r3 * 64 + lane]);
            float f4 = bf2f(x0s[r4 * 64 + lane]);
            float f5 = bf2f(x0s[r5 * 64 + lane]);
            float f6 = bf2f(x0s[r6 * 64 + lane]);
            float f7 = bf2f(x0s[r7 * 64 + lane]);
            acc0 += (f0 + f1) + (f2 + f3);
            acc1 += (f4 + f5) + (f6 + f7);
        }
        for (; j < m; ++j) {
            int r = __shfl(idx, j);
            acc0 += bf2f(x0s[r * 64 + lane]);
        }
    }
    agg[n * 64 + lane] = (acc0 + acc1) * dinv[n];
}

// ---------------------------------------------------------------------------
// 4) per-head 64x64 linear + bias + relu, dual store.
__global__ __launch_bounds__(256) void k_gemm(const float* __restrict__ agg,
                                              const float* __restrict__ W,
                                              const float* __restrict__ b,
                                              float* __restrict__ out0,
                                              float* __restrict__ out1) {
    int t = threadIdx.x;
    int h = t >> 6, o = t & 63;
    float wreg[64];
    #pragma unroll
    for (int f = 0; f < 64; ++f) wreg[f] = W[h * 4096 + f * 64 + o];
    float bias = b[t];
    int n0 = blockIdx.x * 8;   // 6250 * 8 = 50000 exactly
    for (int i = 0; i < 8; ++i) {
        int n = n0 + i;
        const float* __restrict__ arow = agg + n * 64;   // block-uniform address
        float acc = bias;
        #pragma unroll
        for (int f = 0; f < 64; ++f) acc = fmaf(arow[f], wreg[f], acc);
        float v = fmaxf(acc, 0.0f);
        __builtin_nontemporal_store(v, &out0[n * 256 + t]);
        __builtin_nontemporal_store(v, &out1[n * 256 + t]);
    }
}

// ---------------------------------------------------------------------------

extern "C" void kernel_launch(void* const* d_in, const int* in_sizes, int n_in,
                              void* d_out, int out_size, void* d_ws, size_t ws_size,
                              hipStream_t stream) {
    const float* x     = (const float*)d_in[0];   // (50000, 256) f32
    const int*   edges = (const int*)d_in[1];     // (2, 1600000) int32
    const float* W     = (const float*)d_in[2];   // (4, 64, 64) f32
    const float* b     = (const float*)d_in[3];   // (4, 64) f32

    float* out0 = (float*)d_out;                   // x_cat (50000,256)
    float* out1 = out0 + (size_t)NNODES * 256;     // heads (50000,4,64) — same values

    // workspace layout (512B-aligned)
    char* ws = (char*)d_ws;
    int*            bincur = (int*)(ws + 0);              //  25,024 B (8 XCD x 782 bins)
    int*            ovfcnt = (int*)(ws + 25024);          //       4 B
    int*            ovf    = (int*)(ws + 25600);          // 262,144 B
    float*          dinv   = (float*)(ws + 287744);       // 200,000 B
    int*            rowptr = (int*)(ws + 487936);         // 200,000 B
    int*            cntn   = (int*)(ws + 688128);         // 200,000 B
    int*            binned = (int*)(ws + 888320);         // 12,812,288 B (8 x 782 x 512)
    int*            csr    = (int*)(ws + 13700608);       //  9,008,640 B
    unsigned short* x0s    = (unsigned short*)(ws + 22709248);  // 6,400,000 B
    float*          agg    = (float*)(ws + 29109248);     // 12,800,000 B  (total ~41.9 MB)

    hipMemsetAsync(ws, 0, 25028, stream);   // bincur + ovfcnt
    k_bin    <<<NBBLK, 256, 0, stream>>>(edges, bincur, ovfcnt, ovf, binned);
    k_sortbin<<<NBIN, 256, 0, stream>>>(bincur, binned, ovfcnt, ovf, x, rowptr, cntn, dinv, x0s, csr);
    k_gather <<<NNODES / 4, 256, 0, stream>>>(x0s, rowptr, cntn, dinv, csr, agg);
    k_gemm   <<<NNODES / 8, 256, 0, stream>>>(agg, W, b, out0, out1);
}